// Round 6
// baseline (269.410 us; speedup 1.0000x reference)
//
#include <hip/hip_runtime.h>
#include <math.h>

#define BATCH 128
#define ACT 7
#define NC 100
#define CTXD 128
#define HID 512
#define QW 600               // q width (cols 600..699 of reference are exactly 0)

typedef __attribute__((ext_vector_type(8))) __bf16 bf16x8;
typedef __attribute__((ext_vector_type(4))) float f32x4;
typedef __attribute__((ext_vector_type(8))) unsigned short u16x8;
typedef __attribute__((ext_vector_type(4))) unsigned short u16x4;

__device__ __forceinline__ unsigned short f2bf(float f) {
    union { float f; unsigned int u; } v; v.f = f;
    unsigned int u = v.u;
    return (unsigned short)((u + 0x7fffu + ((u >> 16) & 1u)) >> 16);
}

// async global->LDS, 16B per lane. LDS dest = wave-uniform base + lane*16.
__device__ __forceinline__ void async16(const void* g, void* l) {
    __builtin_amdgcn_global_load_lds(
        (const __attribute__((address_space(1))) unsigned int*)(uintptr_t)g,
        (__attribute__((address_space(3))) unsigned int*)(unsigned int)(uintptr_t)l,
        16, 0, 0);
}

// ---------------- cvt: fp32 -> bf16 row-major copies -------------------------
__global__ void cvt_kernel(const float* __restrict__ obs, const float* __restrict__ W1,
                           const float* __restrict__ W2, const float* __restrict__ W3,
                           unsigned short* __restrict__ obs_bf, unsigned short* __restrict__ W1Cbf,
                           unsigned short* __restrict__ W2bf, unsigned short* __restrict__ W3bf) {
    const int e = (blockIdx.x * 256 + threadIdx.x) * 4;   // grid covers 2424832 elems
    const float* src; unsigned short* dst;
    if (e < 65536)        { src = obs + e; dst = obs_bf + e; }
    else if (e < 458752)  { int f = e - 65536; int i = f >> 16; int rem = f & 65535;
                            src = W1 + (size_t)(i + 1) * 328192 + 513*512 + rem; dst = W1Cbf + f; }
    else if (e < 2031616) { int f = e - 458752; src = W2 + 262144 + f; dst = W2bf + f; }
    else                  { int f = e - 2031616; src = W3 + 65536 + f; dst = W3bf + f; }
    float4 v = *(const float4*)src;
    u16x4 o; o[0] = f2bf(v.x); o[1] = f2bf(v.y); o[2] = f2bf(v.z); o[3] = f2bf(v.w);
    *(u16x4*)dst = o;
}

// ---------------- transpose+convert: W1AT / W2T / W3T ------------------------
__global__ void prep_transpose(const float* __restrict__ W1, const float* __restrict__ W2,
                               const float* __restrict__ W3,
                               unsigned short* __restrict__ W1AT, unsigned short* __restrict__ W2T,
                               unsigned short* __restrict__ W3T) {
    __shared__ float tile[32][33];
    const int z = blockIdx.z;
    const float* ip; unsigned short* op; int Cn;
    if (z < 6)       { ip = W1 + (size_t)(z + 1) * 328192; op = W1AT + (size_t)z * 262144; Cn = 512; }
    else if (z < 12) { int i = z - 6;  ip = W2 + (size_t)(i + 1) * 262144; op = W2T + (size_t)i * 262144; Cn = 512; }
    else             { int i = z - 12; ip = W3 + (size_t)(i + 1) * 65536;  op = W3T + (size_t)i * 65536;  Cn = 128;
                       if (blockIdx.y >= 4) return; }
    const int r0 = blockIdx.x * 32, c0 = blockIdx.y * 32;
    const int tx = threadIdx.x, ty = threadIdx.y;  // 32 x 8
    #pragma unroll
    for (int j = 0; j < 32; j += 8)
        tile[ty + j][tx] = ip[(size_t)(r0 + ty + j) * Cn + c0 + tx];
    __syncthreads();
    #pragma unroll
    for (int j = 0; j < 32; j += 8)
        op[(size_t)(c0 + ty + j) * 512 + r0 + tx] = f2bf(tile[tx][ty + j]);
}

// ---------------- Yobs[z][b][h] = obs@W1A[z+1] + b1[z+1] ---------------------
__launch_bounds__(256)
__global__ void yobs_kernel(const unsigned short* __restrict__ A,      // obs_bf [128][512]
                            const unsigned short* __restrict__ BtAll,  // W1AT [6][512][512]
                            const float* __restrict__ b1,
                            float* __restrict__ Yobs) {
    __shared__ unsigned short As[64*32];
    __shared__ unsigned short Bs[128*32];
    const int m0 = blockIdx.x * 64;
    const int n0 = blockIdx.y * 128;
    const int z  = blockIdx.z;
    const unsigned short* Bt = BtAll + (size_t)z * 262144;
    const int tid = threadIdx.x, lane = tid & 63, wave = tid >> 6;
    const int wm = wave >> 1, wn = wave & 1;
    const int srow = tid >> 2, skc = (tid & 3) * 8;
    const unsigned short* gA  = A  + (size_t)(m0 + srow) * HID + skc;
    const unsigned short* gB0 = Bt + (size_t)(n0 + srow) * HID + skc;
    const unsigned short* gB1 = gB0 + 64 * HID;
    f32x4 acc[2][4] = {};
    for (int k0 = 0; k0 < HID; k0 += 32) {
        async16(gA + k0, As + tid*8);
        async16(gB0 + k0, Bs + tid*8);
        async16(gB1 + k0, Bs + 2048 + tid*8);
        __syncthreads();
        const int q8 = (lane >> 4) * 8, l15 = lane & 15;
        bf16x8 af[2], bfr[4];
        #pragma unroll
        for (int mt = 0; mt < 2; ++mt)
            af[mt] = *(const bf16x8*)(As + (wm*32 + mt*16 + l15) * 32 + q8);
        #pragma unroll
        for (int nt = 0; nt < 4; ++nt)
            bfr[nt] = *(const bf16x8*)(Bs + (wn*64 + nt*16 + l15) * 32 + q8);
        #pragma unroll
        for (int mt = 0; mt < 2; ++mt)
            #pragma unroll
            for (int nt = 0; nt < 4; ++nt)
                acc[mt][nt] = __builtin_amdgcn_mfma_f32_16x16x32_bf16(af[mt], bfr[nt], acc[mt][nt], 0, 0, 0);
        __syncthreads();
    }
    const int colL = wn*64 + (lane & 15);
    #pragma unroll
    for (int nt = 0; nt < 4; ++nt) {
        const int col = n0 + colL + nt*16;
        const float bb = b1[(z + 1) * HID + col];
        #pragma unroll
        for (int mt = 0; mt < 2; ++mt)
            #pragma unroll
            for (int r = 0; r < 4; ++r) {
                const int row = m0 + wm*32 + mt*16 + (lane >> 4)*4 + r;
                Yobs[(size_t)z * 65536 + (size_t)row * HID + col] = acc[mt][nt][r] + bb;
            }
    }
}

// ---------------- chain: per-batch serial context chain, 1024 thr, split-K ---
__launch_bounds__(1024)
__global__ void chain_kernel(const float* __restrict__ Yobs, const float* __restrict__ W1,
                             const unsigned short* __restrict__ W1Cbf,
                             const unsigned short* __restrict__ W2bf,
                             const unsigned short* __restrict__ W3bf,
                             const float* __restrict__ b2, const float* __restrict__ b3,
                             const float* __restrict__ actions,
                             float* __restrict__ Y0all, float* __restrict__ CTXS) {
    const int b = blockIdx.x, t = threadIdx.x;
    __shared__ float ctx[128], h1[512], h2s[512];
    __shared__ float part[2048];      // layer1/2: [4][512]; layer3: [16][128]
    const int pair = t & 255, kq = t >> 8;      // layers 1,2
    const int pair3 = t & 63, kq3 = t >> 6;     // layer 3
    if (t < 128) ctx[t] = 0.f;
    __syncthreads();
    for (int i = 1; i <= 6; ++i) {
        if (t < 128) CTXS[(size_t)(i-1)*16384 + b*128 + t] = ctx[t];
        const float a = actions[b*ACT + i];
        float fj = floorf((a + 1.0f) * 50.0f);
        fj = fminf(fmaxf(fj, 0.0f), 99.0f);
        // ---- layer1 ctx part ----
        {
            const unsigned int* wp1 = (const unsigned int*)(W1Cbf + (size_t)(i-1)*65536) + pair;
            float acc0 = 0.f, acc1 = 0.f;
            #pragma unroll 8
            for (int k = kq*32; k < kq*32 + 32; ++k) {
                unsigned int u = wp1[k*256];
                float c = ctx[k];
                acc0 = fmaf(c, __uint_as_float(u << 16), acc0);
                acc1 = fmaf(c, __uint_as_float(u & 0xffff0000u), acc1);
            }
            *(float2*)(&part[kq*512 + 2*pair]) = make_float2(acc0, acc1);
        }
        __syncthreads();
        if (t < 256) {
            const int n2 = 2*t;
            float2 p0 = *(const float2*)(&part[n2]);
            float2 p1 = *(const float2*)(&part[512 + n2]);
            float2 p2 = *(const float2*)(&part[1024 + n2]);
            float2 p3 = *(const float2*)(&part[1536 + n2]);
            float2 yo = *(const float2*)(Yobs + (size_t)(i-1)*65536 + b*512 + n2);
            float y0a = yo.x + p0.x + p1.x + p2.x + p3.x;
            float y0b = yo.y + p0.y + p1.y + p2.y + p3.y;
            *(float2*)(Y0all + (size_t)(i-1)*65536 + b*512 + n2) = make_float2(y0a, y0b);
            const float* w1a = W1 + (size_t)i*328192 + 262144;   // row 512 of W1[i]
            float2 wv = *(const float2*)(w1a + n2);
            h1[n2]   = fmaxf(fmaf(fj, wv.x, y0a), 0.f);
            h1[n2+1] = fmaxf(fmaf(fj, wv.y, y0b), 0.f);
        }
        __syncthreads();
        // ---- layer2 ----
        {
            const unsigned int* wp2 = (const unsigned int*)(W2bf + (size_t)(i-1)*262144) + pair;
            float acc0 = 0.f, acc1 = 0.f;
            #pragma unroll 16
            for (int k = kq*128; k < kq*128 + 128; ++k) {
                unsigned int u = wp2[k*256];
                float hv = h1[k];
                acc0 = fmaf(hv, __uint_as_float(u << 16), acc0);
                acc1 = fmaf(hv, __uint_as_float(u & 0xffff0000u), acc1);
            }
            *(float2*)(&part[kq*512 + 2*pair]) = make_float2(acc0, acc1);
        }
        __syncthreads();
        if (t < 256) {
            const int n2 = 2*t;
            float2 p0 = *(const float2*)(&part[n2]);
            float2 p1 = *(const float2*)(&part[512 + n2]);
            float2 p2 = *(const float2*)(&part[1024 + n2]);
            float2 p3 = *(const float2*)(&part[1536 + n2]);
            float2 bb = *(const float2*)(b2 + i*512 + n2);
            h2s[n2]   = fmaxf(p0.x + p1.x + p2.x + p3.x + bb.x, 0.f);
            h2s[n2+1] = fmaxf(p0.y + p1.y + p2.y + p3.y + bb.y, 0.f);
        }
        __syncthreads();
        // ---- layer3 ----
        {
            const unsigned int* wp3 = (const unsigned int*)(W3bf + (size_t)(i-1)*65536) + pair3;
            float acc0 = 0.f, acc1 = 0.f;
            #pragma unroll 8
            for (int k = kq3*32; k < kq3*32 + 32; ++k) {
                unsigned int u = wp3[k*64];
                float hv = h2s[k];
                acc0 = fmaf(hv, __uint_as_float(u << 16), acc0);
                acc1 = fmaf(hv, __uint_as_float(u & 0xffff0000u), acc1);
            }
            *(float2*)(&part[kq3*128 + 2*pair3]) = make_float2(acc0, acc1);
        }
        __syncthreads();
        if (t < 128) {
            float s = 0.f;
            #pragma unroll
            for (int qg = 0; qg < 16; ++qg) s += part[qg*128 + t];
            ctx[t] = s + b3[i*128 + t] + ctx[t];
        }
        __syncthreads();
    }
}

// ---------------- h2all v3: M=64 blocks, full N=512 per k-loop ---------------
// H2 = bf16(relu(relu(Y0+c*w1a) @ W2 + b2)); A-fill done once per element.
// 4 waves arranged 1m x 4n; wave tile 64x128 (4 mt x 8 nt); acc 128 VGPR.
__launch_bounds__(256, 2)
__global__ void h2all_kernel(const float* __restrict__ Y0all, const float* __restrict__ W1,
                             const unsigned short* __restrict__ W2T, const float* __restrict__ b2,
                             unsigned short* __restrict__ H2) {
    __shared__ unsigned short ASl[64*32];    // 4 KB
    __shared__ unsigned short BSl[512*32];   // 32 KB
    const int bx = blockIdx.x;               // 0..1199
    const int z  = bx / 200;
    const int r0 = bx * 64;                  // global row
    const int r2 = (bx % 200) * 64;          // row within iteration z
    const int tid = threadIdx.x, lane = tid & 63, wave = tid >> 6;  // wn = wave
    const int l15 = lane & 15, q8 = (lane >> 4) * 8;
    // A-fill assignment: one u16x8 chunk per thread
    const int rA = tid >> 2, kc8 = (tid & 3) * 8;
    const int growA = r2 + rA;
    const float cA = (float)(growA % 100);
    const float* yp  = Y0all + (size_t)z*65536 + (size_t)(growA/100)*512 + kc8;
    const float* w1a = W1 + (size_t)(z+1)*328192 + 262144 + kc8;
    // B staging: 8 async16/thread; slot s = c*256 + wave*64 + lane, col = s>>2, sub = s&3
    const unsigned short* W2Tz = W2T + (size_t)z*262144;
    f32x4 acc[4][8] = {};
    for (int k0 = 0; k0 < 512; k0 += 32) {
        // A-slab: relu(Y0 + c*w1a) -> bf16
        {
            float4 y0v = *(const float4*)(yp + k0);
            float4 y1v = *(const float4*)(yp + k0 + 4);
            float4 w0v = *(const float4*)(w1a + k0);
            float4 w1v = *(const float4*)(w1a + k0 + 4);
            u16x8 o;
            o[0] = f2bf(fmaxf(fmaf(cA, w0v.x, y0v.x), 0.f));
            o[1] = f2bf(fmaxf(fmaf(cA, w0v.y, y0v.y), 0.f));
            o[2] = f2bf(fmaxf(fmaf(cA, w0v.z, y0v.z), 0.f));
            o[3] = f2bf(fmaxf(fmaf(cA, w0v.w, y0v.w), 0.f));
            o[4] = f2bf(fmaxf(fmaf(cA, w1v.x, y1v.x), 0.f));
            o[5] = f2bf(fmaxf(fmaf(cA, w1v.y, y1v.y), 0.f));
            o[6] = f2bf(fmaxf(fmaf(cA, w1v.z, y1v.z), 0.f));
            o[7] = f2bf(fmaxf(fmaf(cA, w1v.w, y1v.w), 0.f));
            *(u16x8*)(ASl + rA*32 + kc8) = o;
        }
        // B-slab: 512 cols x 32 k via 8 async16/thread
        #pragma unroll
        for (int c = 0; c < 8; ++c) {
            const int s = c*256 + wave*64 + lane;
            const int col = s >> 2, sub = s & 3;
            async16(W2Tz + (size_t)col*512 + k0 + sub*8, BSl + (size_t)s*8);
        }
        __syncthreads();
        bf16x8 af[4], bfr[8];
        #pragma unroll
        for (int mt = 0; mt < 4; ++mt)
            af[mt] = *(const bf16x8*)(ASl + (mt*16 + l15)*32 + q8);
        #pragma unroll
        for (int nt = 0; nt < 8; ++nt)
            bfr[nt] = *(const bf16x8*)(BSl + (wave*128 + nt*16 + l15)*32 + q8);
        #pragma unroll
        for (int mt = 0; mt < 4; ++mt)
            #pragma unroll
            for (int nt = 0; nt < 8; ++nt)
                acc[mt][nt] = __builtin_amdgcn_mfma_f32_16x16x32_bf16(af[mt], bfr[nt], acc[mt][nt], 0, 0, 0);
        __syncthreads();
    }
    #pragma unroll
    for (int nt = 0; nt < 8; ++nt) {
        const int col = wave*128 + nt*16 + l15;
        const float bb = b2[(z+1)*512 + col];
        #pragma unroll
        for (int mt = 0; mt < 4; ++mt)
            #pragma unroll
            for (int r = 0; r < 4; ++r) {
                const int row = r0 + mt*16 + (lane >> 4)*4 + r;
                H2[(size_t)row * 512 + col] = f2bf(fmaxf(acc[mt][nt][r] + bb, 0.f));
            }
    }
}

// ---------------- gemm3all v2: M=64 tiles, fused q epilogue ------------------
__launch_bounds__(256)
__global__ void gemm3all_kernel(const unsigned short* __restrict__ H2,
                                const unsigned short* __restrict__ W3T,
                                const float* __restrict__ b3, const float* __restrict__ CTXS,
                                const float* __restrict__ Wp, const float* __restrict__ bp,
                                float* __restrict__ q) {
    __shared__ unsigned short ASl[64*32];    // 4 KB
    __shared__ unsigned short BSl[128*32];   // 8 KB
    __shared__ float CCs[64][132];
    __shared__ float qp[64][4];
    const int bx = blockIdx.x;               // 0..1199
    const int z  = bx / 200;
    const int r0 = bx * 64;                  // global H2 row
    const int r2 = (bx % 200) * 64;          // row within iteration z
    const int tid = threadIdx.x, lane = tid & 63, wave = tid >> 6;
    const int wm = wave >> 1, wn = wave & 1;
    const int l15 = lane & 15, q8 = (lane >> 4) * 8;
    const unsigned short* W3Tz = W3T + (size_t)z*65536;
    f32x4 acc[2][4] = {};
    for (int k0 = 0; k0 < 512; k0 += 32) {
        // A: 64 rows x 32 k (256 slots, 1/thread)
        {
            const int s = wave*64 + lane, row = s >> 2, sub = s & 3;
            async16(H2 + (size_t)(r0 + row)*512 + k0 + sub*8, ASl + (size_t)s*8);
        }
        // B: 128 cols x 32 k (512 slots, 2/thread)
        #pragma unroll
        for (int c = 0; c < 2; ++c) {
            const int s = c*256 + wave*64 + lane, col = s >> 2, sub = s & 3;
            async16(W3Tz + (size_t)col*512 + k0 + sub*8, BSl + (size_t)s*8);
        }
        __syncthreads();
        bf16x8 af[2], bfr[4];
        #pragma unroll
        for (int mt = 0; mt < 2; ++mt)
            af[mt] = *(const bf16x8*)(ASl + (wm*32 + mt*16 + l15)*32 + q8);
        #pragma unroll
        for (int nt = 0; nt < 4; ++nt)
            bfr[nt] = *(const bf16x8*)(BSl + (wn*64 + nt*16 + l15)*32 + q8);
        #pragma unroll
        for (int mt = 0; mt < 2; ++mt)
            #pragma unroll
            for (int nt = 0; nt < 4; ++nt)
                acc[mt][nt] = __builtin_amdgcn_mfma_f32_16x16x32_bf16(af[mt], bfr[nt], acc[mt][nt], 0, 0, 0);
        __syncthreads();
    }
    #pragma unroll
    for (int nt = 0; nt < 4; ++nt) {
        const int col = wn*64 + nt*16 + l15;
        const float bb = b3[(z+1)*128 + col];
        #pragma unroll
        for (int mt = 0; mt < 2; ++mt)
            #pragma unroll
            for (int r = 0; r < 4; ++r) {
                const int rowL = wm*32 + mt*16 + (lane >> 4)*4 + r;
                const int gb = (r2 + rowL) / 100;
                CCs[rowL][col] = acc[mt][nt][r] + bb + CTXS[(size_t)z*16384 + gb*128 + col];
            }
    }
    __syncthreads();
    {
        const int rowL = tid >> 2, seg = tid & 3;
        float s = 0.f;
        #pragma unroll
        for (int j = 0; j < 32; ++j) s += CCs[rowL][seg*32 + j] * Wp[seg*32 + j];
        qp[rowL][seg] = s;
    }
    __syncthreads();
    if (tid < 64) {
        const int gr2 = r2 + tid;
        const int gb = gr2 / 100, gc = gr2 - gb * 100;
        float s = qp[tid][0] + qp[tid][1] + qp[tid][2] + qp[tid][3];
        q[gb * QW + z * 100 + gc] = s + bp[0];
    }
}

// ---------------- out[b] = logsumexp([q[b,0:600], zeros(100)]) ---------------
__global__ void lse_kernel(const float* __restrict__ q, float* __restrict__ out) {
    __shared__ float red[256];
    int b = blockIdx.x, t = threadIdx.x;
    float m = 0.0f;   // zero tail participates in the max
    for (int k = t; k < QW; k += 256) m = fmaxf(m, q[b*QW + k]);
    red[t] = m; __syncthreads();
    for (int s = 128; s > 0; s >>= 1) { if (t < s) red[t] = fmaxf(red[t], red[t+s]); __syncthreads(); }
    m = red[0]; __syncthreads();
    float sum = 0.0f;
    for (int k = t; k < QW; k += 256) sum += expf(q[b*QW + k] - m);
    red[t] = sum; __syncthreads();
    for (int s = 128; s > 0; s >>= 1) { if (t < s) red[t] += red[t+s]; __syncthreads(); }
    if (t == 0) out[b] = logf(red[0] + 100.0f * expf(-m)) + m;
}

extern "C" void kernel_launch(void* const* d_in, const int* in_sizes, int n_in,
                              void* d_out, int out_size, void* d_ws, size_t ws_size,
                              hipStream_t stream) {
    const float* obs     = (const float*)d_in[0];
    const float* actions = (const float*)d_in[1];
    const float* W1      = (const float*)d_in[2];
    const float* b1      = (const float*)d_in[3];
    const float* W2      = (const float*)d_in[4];
    const float* b2      = (const float*)d_in[5];
    const float* W3      = (const float*)d_in[6];
    const float* b3      = (const float*)d_in[7];
    const float* Wp      = (const float*)d_in[8];
    const float* bp      = (const float*)d_in[9];
    float* out = (float*)d_out;
    float* ws  = (float*)d_ws;

    // workspace layout (float offsets)
    unsigned short* obs_bf = (unsigned short*)(ws);            // 32768 f
    unsigned short* W1AT   = (unsigned short*)(ws + 32768);    // 786432 f
    unsigned short* W2T    = (unsigned short*)(ws + 819200);   // 786432 f
    unsigned short* W3T    = (unsigned short*)(ws + 1605632);  // 196608 f
    unsigned short* W1Cbf  = (unsigned short*)(ws + 1802240);  // 196608 f
    unsigned short* W2bf   = (unsigned short*)(ws + 1998848);  // 786432 f
    unsigned short* W3bf   = (unsigned short*)(ws + 2785280);  // 196608 f
    float* Yobs  = ws + 2981888;                               // 393216 f
    float* Y0all = ws + 3375104;                               // 393216 f
    float* CTXS  = ws + 3768320;                               // 98304 f
    float* q     = ws + 3866624;                               // 76800 f
    unsigned short* H2 = (unsigned short*)(ws + 3943424);      // 19660800 f

    cvt_kernel<<<2368, 256, 0, stream>>>(obs, W1, W2, W3, obs_bf, W1Cbf, W2bf, W3bf);
    prep_transpose<<<dim3(16,16,18), dim3(32,8), 0, stream>>>(W1, W2, W3, W1AT, W2T, W3T);
    yobs_kernel<<<dim3(2,4,6), 256, 0, stream>>>(obs_bf, W1AT, b1, Yobs);
    chain_kernel<<<BATCH, 1024, 0, stream>>>(Yobs, W1, W1Cbf, W2bf, W3bf, b2, b3, actions, Y0all, CTXS);
    h2all_kernel<<<1200, 256, 0, stream>>>(Y0all, W1, W2T, b2, H2);
    gemm3all_kernel<<<1200, 256, 0, stream>>>(H2, W3T, b3, CTXS, Wp, bp, q);
    lse_kernel<<<BATCH, 256, 0, stream>>>(q, out);
}

// Round 7
// 259.402 us; speedup vs baseline: 1.0386x; 1.0386x over previous
//
#include <hip/hip_runtime.h>
#include <math.h>

#define BATCH 128
#define ACT 7
#define NC 100
#define CTXD 128
#define HID 512
#define QW 600               // q width (cols 600..699 of reference are exactly 0)

typedef __attribute__((ext_vector_type(8))) __bf16 bf16x8;
typedef __attribute__((ext_vector_type(4))) float f32x4;
typedef __attribute__((ext_vector_type(8))) unsigned short u16x8;
typedef __attribute__((ext_vector_type(4))) unsigned short u16x4;

__device__ __forceinline__ unsigned short f2bf(float f) {
    union { float f; unsigned int u; } v; v.f = f;
    unsigned int u = v.u;
    return (unsigned short)((u + 0x7fffu + ((u >> 16) & 1u)) >> 16);
}

// fast round-half-up bf16: (u + 0x8000) >> 16  (error bound == RNE except ties)
__device__ __forceinline__ unsigned short f2bf_fast(float f) {
    return (unsigned short)((__float_as_uint(f) + 0x8000u) >> 16);
}
// pack two floats -> two bf16 in one uint (lo = a, hi = b)
__device__ __forceinline__ unsigned int pack2bf(float a, float b) {
    unsigned int ua = __float_as_uint(a) + 0x8000u;
    unsigned int ub = __float_as_uint(b) + 0x8000u;
    return (ua >> 16) | (ub & 0xffff0000u);
}

// async global->LDS, 16B per lane. LDS dest = wave-uniform base + lane*16.
__device__ __forceinline__ void async16(const void* g, void* l) {
    __builtin_amdgcn_global_load_lds(
        (const __attribute__((address_space(1))) unsigned int*)(uintptr_t)g,
        (__attribute__((address_space(3))) unsigned int*)(unsigned int)(uintptr_t)l,
        16, 0, 0);
}

// ---------------- cvt: fp32 -> bf16 row-major copies -------------------------
__global__ void cvt_kernel(const float* __restrict__ obs, const float* __restrict__ W1,
                           const float* __restrict__ W2, const float* __restrict__ W3,
                           unsigned short* __restrict__ obs_bf, unsigned short* __restrict__ W1Cbf,
                           unsigned short* __restrict__ W2bf, unsigned short* __restrict__ W3bf) {
    const int e = (blockIdx.x * 256 + threadIdx.x) * 4;   // grid covers 2424832 elems
    const float* src; unsigned short* dst;
    if (e < 65536)        { src = obs + e; dst = obs_bf + e; }
    else if (e < 458752)  { int f = e - 65536; int i = f >> 16; int rem = f & 65535;
                            src = W1 + (size_t)(i + 1) * 328192 + 513*512 + rem; dst = W1Cbf + f; }
    else if (e < 2031616) { int f = e - 458752; src = W2 + 262144 + f; dst = W2bf + f; }
    else                  { int f = e - 2031616; src = W3 + 65536 + f; dst = W3bf + f; }
    float4 v = *(const float4*)src;
    u16x4 o; o[0] = f2bf(v.x); o[1] = f2bf(v.y); o[2] = f2bf(v.z); o[3] = f2bf(v.w);
    *(u16x4*)dst = o;
}

// ---------------- transpose+convert: W1AT / W2T / W3T ------------------------
__global__ void prep_transpose(const float* __restrict__ W1, const float* __restrict__ W2,
                               const float* __restrict__ W3,
                               unsigned short* __restrict__ W1AT, unsigned short* __restrict__ W2T,
                               unsigned short* __restrict__ W3T) {
    __shared__ float tile[32][33];
    const int z = blockIdx.z;
    const float* ip; unsigned short* op; int Cn;
    if (z < 6)       { ip = W1 + (size_t)(z + 1) * 328192; op = W1AT + (size_t)z * 262144; Cn = 512; }
    else if (z < 12) { int i = z - 6;  ip = W2 + (size_t)(i + 1) * 262144; op = W2T + (size_t)i * 262144; Cn = 512; }
    else             { int i = z - 12; ip = W3 + (size_t)(i + 1) * 65536;  op = W3T + (size_t)i * 65536;  Cn = 128;
                       if (blockIdx.y >= 4) return; }
    const int r0 = blockIdx.x * 32, c0 = blockIdx.y * 32;
    const int tx = threadIdx.x, ty = threadIdx.y;  // 32 x 8
    #pragma unroll
    for (int j = 0; j < 32; j += 8)
        tile[ty + j][tx] = ip[(size_t)(r0 + ty + j) * Cn + c0 + tx];
    __syncthreads();
    #pragma unroll
    for (int j = 0; j < 32; j += 8)
        op[(size_t)(c0 + ty + j) * 512 + r0 + tx] = f2bf(tile[tx][ty + j]);
}

// ---------------- Yobs[z][b][h] = obs@W1A[z+1] + b1[z+1] ---------------------
__launch_bounds__(256)
__global__ void yobs_kernel(const unsigned short* __restrict__ A,      // obs_bf [128][512]
                            const unsigned short* __restrict__ BtAll,  // W1AT [6][512][512]
                            const float* __restrict__ b1,
                            float* __restrict__ Yobs) {
    __shared__ unsigned short As[64*32];
    __shared__ unsigned short Bs[128*32];
    const int m0 = blockIdx.x * 64;
    const int n0 = blockIdx.y * 128;
    const int z  = blockIdx.z;
    const unsigned short* Bt = BtAll + (size_t)z * 262144;
    const int tid = threadIdx.x, lane = tid & 63, wave = tid >> 6;
    const int wm = wave >> 1, wn = wave & 1;
    const int srow = tid >> 2, skc = (tid & 3) * 8;
    const unsigned short* gA  = A  + (size_t)(m0 + srow) * HID + skc;
    const unsigned short* gB0 = Bt + (size_t)(n0 + srow) * HID + skc;
    const unsigned short* gB1 = gB0 + 64 * HID;
    f32x4 acc[2][4] = {};
    for (int k0 = 0; k0 < HID; k0 += 32) {
        async16(gA + k0, As + tid*8);
        async16(gB0 + k0, Bs + tid*8);
        async16(gB1 + k0, Bs + 2048 + tid*8);
        __syncthreads();
        const int q8 = (lane >> 4) * 8, l15 = lane & 15;
        bf16x8 af[2], bfr[4];
        #pragma unroll
        for (int mt = 0; mt < 2; ++mt)
            af[mt] = *(const bf16x8*)(As + (wm*32 + mt*16 + l15) * 32 + q8);
        #pragma unroll
        for (int nt = 0; nt < 4; ++nt)
            bfr[nt] = *(const bf16x8*)(Bs + (wn*64 + nt*16 + l15) * 32 + q8);
        #pragma unroll
        for (int mt = 0; mt < 2; ++mt)
            #pragma unroll
            for (int nt = 0; nt < 4; ++nt)
                acc[mt][nt] = __builtin_amdgcn_mfma_f32_16x16x32_bf16(af[mt], bfr[nt], acc[mt][nt], 0, 0, 0);
        __syncthreads();
    }
    const int colL = wn*64 + (lane & 15);
    #pragma unroll
    for (int nt = 0; nt < 4; ++nt) {
        const int col = n0 + colL + nt*16;
        const float bb = b1[(z + 1) * HID + col];
        #pragma unroll
        for (int mt = 0; mt < 2; ++mt)
            #pragma unroll
            for (int r = 0; r < 4; ++r) {
                const int row = m0 + wm*32 + mt*16 + (lane >> 4)*4 + r;
                Yobs[(size_t)z * 65536 + (size_t)row * HID + col] = acc[mt][nt][r] + bb;
            }
    }
}

// ---------------- chain: per-batch serial context chain, 1024 thr, split-K ---
__launch_bounds__(1024)
__global__ void chain_kernel(const float* __restrict__ Yobs, const float* __restrict__ W1,
                             const unsigned short* __restrict__ W1Cbf,
                             const unsigned short* __restrict__ W2bf,
                             const unsigned short* __restrict__ W3bf,
                             const float* __restrict__ b2, const float* __restrict__ b3,
                             const float* __restrict__ actions,
                             float* __restrict__ Y0all, float* __restrict__ CTXS) {
    const int b = blockIdx.x, t = threadIdx.x;
    __shared__ float ctx[128], h1[512], h2s[512];
    __shared__ float part[2048];      // layer1/2: [4][512]; layer3: [16][128]
    const int pair = t & 255, kq = t >> 8;      // layers 1,2
    const int pair3 = t & 63, kq3 = t >> 6;     // layer 3
    if (t < 128) ctx[t] = 0.f;
    __syncthreads();
    for (int i = 1; i <= 6; ++i) {
        if (t < 128) CTXS[(size_t)(i-1)*16384 + b*128 + t] = ctx[t];
        const float a = actions[b*ACT + i];
        float fj = floorf((a + 1.0f) * 50.0f);
        fj = fminf(fmaxf(fj, 0.0f), 99.0f);
        // ---- layer1 ctx part ----
        {
            const unsigned int* wp1 = (const unsigned int*)(W1Cbf + (size_t)(i-1)*65536) + pair;
            float acc0 = 0.f, acc1 = 0.f;
            #pragma unroll 8
            for (int k = kq*32; k < kq*32 + 32; ++k) {
                unsigned int u = wp1[k*256];
                float c = ctx[k];
                acc0 = fmaf(c, __uint_as_float(u << 16), acc0);
                acc1 = fmaf(c, __uint_as_float(u & 0xffff0000u), acc1);
            }
            *(float2*)(&part[kq*512 + 2*pair]) = make_float2(acc0, acc1);
        }
        __syncthreads();
        if (t < 256) {
            const int n2 = 2*t;
            float2 p0 = *(const float2*)(&part[n2]);
            float2 p1 = *(const float2*)(&part[512 + n2]);
            float2 p2 = *(const float2*)(&part[1024 + n2]);
            float2 p3 = *(const float2*)(&part[1536 + n2]);
            float2 yo = *(const float2*)(Yobs + (size_t)(i-1)*65536 + b*512 + n2);
            float y0a = yo.x + p0.x + p1.x + p2.x + p3.x;
            float y0b = yo.y + p0.y + p1.y + p2.y + p3.y;
            *(float2*)(Y0all + (size_t)(i-1)*65536 + b*512 + n2) = make_float2(y0a, y0b);
            const float* w1a = W1 + (size_t)i*328192 + 262144;   // row 512 of W1[i]
            float2 wv = *(const float2*)(w1a + n2);
            h1[n2]   = fmaxf(fmaf(fj, wv.x, y0a), 0.f);
            h1[n2+1] = fmaxf(fmaf(fj, wv.y, y0b), 0.f);
        }
        __syncthreads();
        // ---- layer2 ----
        {
            const unsigned int* wp2 = (const unsigned int*)(W2bf + (size_t)(i-1)*262144) + pair;
            float acc0 = 0.f, acc1 = 0.f;
            #pragma unroll 16
            for (int k = kq*128; k < kq*128 + 128; ++k) {
                unsigned int u = wp2[k*256];
                float hv = h1[k];
                acc0 = fmaf(hv, __uint_as_float(u << 16), acc0);
                acc1 = fmaf(hv, __uint_as_float(u & 0xffff0000u), acc1);
            }
            *(float2*)(&part[kq*512 + 2*pair]) = make_float2(acc0, acc1);
        }
        __syncthreads();
        if (t < 256) {
            const int n2 = 2*t;
            float2 p0 = *(const float2*)(&part[n2]);
            float2 p1 = *(const float2*)(&part[512 + n2]);
            float2 p2 = *(const float2*)(&part[1024 + n2]);
            float2 p3 = *(const float2*)(&part[1536 + n2]);
            float2 bb = *(const float2*)(b2 + i*512 + n2);
            h2s[n2]   = fmaxf(p0.x + p1.x + p2.x + p3.x + bb.x, 0.f);
            h2s[n2+1] = fmaxf(p0.y + p1.y + p2.y + p3.y + bb.y, 0.f);
        }
        __syncthreads();
        // ---- layer3 ----
        {
            const unsigned int* wp3 = (const unsigned int*)(W3bf + (size_t)(i-1)*65536) + pair3;
            float acc0 = 0.f, acc1 = 0.f;
            #pragma unroll 8
            for (int k = kq3*32; k < kq3*32 + 32; ++k) {
                unsigned int u = wp3[k*64];
                float hv = h2s[k];
                acc0 = fmaf(hv, __uint_as_float(u << 16), acc0);
                acc1 = fmaf(hv, __uint_as_float(u & 0xffff0000u), acc1);
            }
            *(float2*)(&part[kq3*128 + 2*pair3]) = make_float2(acc0, acc1);
        }
        __syncthreads();
        if (t < 128) {
            float s = 0.f;
            #pragma unroll
            for (int qg = 0; qg < 16; ++qg) s += part[qg*128 + t];
            ctx[t] = s + b3[i*128 + t] + ctx[t];
        }
        __syncthreads();
    }
}

// ---------------- h2all v4: M=128 x N=256 tiles, BK=32, fast bf16 pack -------
// H2 = bf16(relu(relu(Y0+c*w1a) @ W2 + b2)). A redundancy 2x, B 4 async16/thr.
// 4 waves as 2m x 2n; wave tile 64x128; acc[4][8] = 128 VGPR.
__launch_bounds__(256, 2)
__global__ void h2all_kernel(const float* __restrict__ Y0all, const float* __restrict__ W1,
                             const unsigned short* __restrict__ W2T, const float* __restrict__ b2,
                             unsigned short* __restrict__ H2) {
    __shared__ unsigned short ASl[128*32];   // 8 KB
    __shared__ unsigned short BSl[256*32];   // 16 KB
    const int bx = blockIdx.x;               // 0..599
    const int z  = bx / 100;
    const int r2 = (bx % 100) * 128;         // row within iteration z
    const int r0 = z * 12800 + r2;           // global row
    const int n0 = blockIdx.y * 256;
    const int tid = threadIdx.x, lane = tid & 63, wave = tid >> 6;
    const int wm = wave >> 1, wn = wave & 1;
    const int l15 = lane & 15, q8 = (lane >> 4) * 8;
    // A-fill: 2 chunks/thread: rows rA, rA+64, k-chunk kc8
    const int rA = tid >> 2, kc8 = (tid & 3) * 8;
    const int g1 = r2 + rA, g2 = r2 + rA + 64;
    const float c1 = (float)(g1 % 100), c2 = (float)(g2 % 100);
    const float* y1p = Y0all + (size_t)z*65536 + (size_t)(g1/100)*512 + kc8;
    const float* y2p = Y0all + (size_t)z*65536 + (size_t)(g2/100)*512 + kc8;
    const float* w1a = W1 + (size_t)(z+1)*328192 + 262144 + kc8;
    const unsigned short* Bbase = W2T + (size_t)z*262144 + (size_t)n0*512;
    f32x4 acc[4][8] = {};
    for (int k0 = 0; k0 < 512; k0 += 32) {
        // A-slab: relu(Y0 + c*w1a) -> bf16 (round-half-up, pair-packed)
        {
            float4 wa = *(const float4*)(w1a + k0);
            float4 wb = *(const float4*)(w1a + k0 + 4);
            float4 ya = *(const float4*)(y1p + k0);
            float4 yb = *(const float4*)(y1p + k0 + 4);
            uint4 o;
            o.x = pack2bf(fmaxf(fmaf(c1, wa.x, ya.x), 0.f), fmaxf(fmaf(c1, wa.y, ya.y), 0.f));
            o.y = pack2bf(fmaxf(fmaf(c1, wa.z, ya.z), 0.f), fmaxf(fmaf(c1, wa.w, ya.w), 0.f));
            o.z = pack2bf(fmaxf(fmaf(c1, wb.x, yb.x), 0.f), fmaxf(fmaf(c1, wb.y, yb.y), 0.f));
            o.w = pack2bf(fmaxf(fmaf(c1, wb.z, yb.z), 0.f), fmaxf(fmaf(c1, wb.w, yb.w), 0.f));
            *(uint4*)(ASl + rA*32 + kc8) = o;
            float4 yc = *(const float4*)(y2p + k0);
            float4 yd = *(const float4*)(y2p + k0 + 4);
            o.x = pack2bf(fmaxf(fmaf(c2, wa.x, yc.x), 0.f), fmaxf(fmaf(c2, wa.y, yc.y), 0.f));
            o.y = pack2bf(fmaxf(fmaf(c2, wa.z, yc.z), 0.f), fmaxf(fmaf(c2, wa.w, yc.w), 0.f));
            o.z = pack2bf(fmaxf(fmaf(c2, wb.x, yd.x), 0.f), fmaxf(fmaf(c2, wb.y, yd.y), 0.f));
            o.w = pack2bf(fmaxf(fmaf(c2, wb.z, yd.z), 0.f), fmaxf(fmaf(c2, wb.w, yd.w), 0.f));
            *(uint4*)(ASl + (rA + 64)*32 + kc8) = o;
        }
        // B-slab: 256 cols x 32 k via 4 async16/thread
        #pragma unroll
        for (int c = 0; c < 4; ++c) {
            const int s = c*256 + tid;
            const int col = s >> 2, sub = s & 3;
            async16(Bbase + (size_t)col*512 + k0 + sub*8, BSl + (size_t)s*8);
        }
        __syncthreads();
        bf16x8 af[4], bfr[8];
        #pragma unroll
        for (int mt = 0; mt < 4; ++mt)
            af[mt] = *(const bf16x8*)(ASl + (wm*64 + mt*16 + l15)*32 + q8);
        #pragma unroll
        for (int nt = 0; nt < 8; ++nt)
            bfr[nt] = *(const bf16x8*)(BSl + (wn*128 + nt*16 + l15)*32 + q8);
        #pragma unroll
        for (int mt = 0; mt < 4; ++mt)
            #pragma unroll
            for (int nt = 0; nt < 8; ++nt)
                acc[mt][nt] = __builtin_amdgcn_mfma_f32_16x16x32_bf16(af[mt], bfr[nt], acc[mt][nt], 0, 0, 0);
        __syncthreads();
    }
    #pragma unroll
    for (int nt = 0; nt < 8; ++nt) {
        const int col = n0 + wn*128 + nt*16 + l15;
        const float bb = b2[(z+1)*512 + col];
        #pragma unroll
        for (int mt = 0; mt < 4; ++mt)
            #pragma unroll
            for (int r = 0; r < 4; ++r) {
                const int row = r0 + wm*64 + mt*16 + (lane >> 4)*4 + r;
                H2[(size_t)row * 512 + col] = f2bf_fast(fmaxf(acc[mt][nt][r] + bb, 0.f));
            }
    }
}

// ---------------- gemm3all v2: M=64 tiles, fused q epilogue ------------------
__launch_bounds__(256)
__global__ void gemm3all_kernel(const unsigned short* __restrict__ H2,
                                const unsigned short* __restrict__ W3T,
                                const float* __restrict__ b3, const float* __restrict__ CTXS,
                                const float* __restrict__ Wp, const float* __restrict__ bp,
                                float* __restrict__ q) {
    __shared__ unsigned short ASl[64*32];    // 4 KB
    __shared__ unsigned short BSl[128*32];   // 8 KB
    __shared__ float CCs[64][132];
    __shared__ float qp[64][4];
    const int bx = blockIdx.x;               // 0..1199
    const int z  = bx / 200;
    const int r0 = bx * 64;                  // global H2 row
    const int r2 = (bx % 200) * 64;          // row within iteration z
    const int tid = threadIdx.x, lane = tid & 63, wave = tid >> 6;
    const int wm = wave >> 1, wn = wave & 1;
    const int l15 = lane & 15, q8 = (lane >> 4) * 8;
    const unsigned short* W3Tz = W3T + (size_t)z*65536;
    f32x4 acc[2][4] = {};
    for (int k0 = 0; k0 < 512; k0 += 32) {
        {
            const int s = wave*64 + lane, row = s >> 2, sub = s & 3;
            async16(H2 + (size_t)(r0 + row)*512 + k0 + sub*8, ASl + (size_t)s*8);
        }
        #pragma unroll
        for (int c = 0; c < 2; ++c) {
            const int s = c*256 + wave*64 + lane, col = s >> 2, sub = s & 3;
            async16(W3Tz + (size_t)col*512 + k0 + sub*8, BSl + (size_t)s*8);
        }
        __syncthreads();
        bf16x8 af[2], bfr[4];
        #pragma unroll
        for (int mt = 0; mt < 2; ++mt)
            af[mt] = *(const bf16x8*)(ASl + (wm*32 + mt*16 + l15)*32 + q8);
        #pragma unroll
        for (int nt = 0; nt < 4; ++nt)
            bfr[nt] = *(const bf16x8*)(BSl + (wn*64 + nt*16 + l15)*32 + q8);
        #pragma unroll
        for (int mt = 0; mt < 2; ++mt)
            #pragma unroll
            for (int nt = 0; nt < 4; ++nt)
                acc[mt][nt] = __builtin_amdgcn_mfma_f32_16x16x32_bf16(af[mt], bfr[nt], acc[mt][nt], 0, 0, 0);
        __syncthreads();
    }
    #pragma unroll
    for (int nt = 0; nt < 4; ++nt) {
        const int col = wn*64 + nt*16 + l15;
        const float bb = b3[(z+1)*128 + col];
        #pragma unroll
        for (int mt = 0; mt < 2; ++mt)
            #pragma unroll
            for (int r = 0; r < 4; ++r) {
                const int rowL = wm*32 + mt*16 + (lane >> 4)*4 + r;
                const int gb = (r2 + rowL) / 100;
                CCs[rowL][col] = acc[mt][nt][r] + bb + CTXS[(size_t)z*16384 + gb*128 + col];
            }
    }
    __syncthreads();
    {
        const int rowL = tid >> 2, seg = tid & 3;
        float s = 0.f;
        #pragma unroll
        for (int j = 0; j < 32; ++j) s += CCs[rowL][seg*32 + j] * Wp[seg*32 + j];
        qp[rowL][seg] = s;
    }
    __syncthreads();
    if (tid < 64) {
        const int gr2 = r2 + tid;
        const int gb = gr2 / 100, gc = gr2 - gb * 100;
        float s = qp[tid][0] + qp[tid][1] + qp[tid][2] + qp[tid][3];
        q[gb * QW + z * 100 + gc] = s + bp[0];
    }
}

// ---------------- out[b] = logsumexp([q[b,0:600], zeros(100)]) ---------------
__global__ void lse_kernel(const float* __restrict__ q, float* __restrict__ out) {
    __shared__ float red[256];
    int b = blockIdx.x, t = threadIdx.x;
    float m = 0.0f;   // zero tail participates in the max
    for (int k = t; k < QW; k += 256) m = fmaxf(m, q[b*QW + k]);
    red[t] = m; __syncthreads();
    for (int s = 128; s > 0; s >>= 1) { if (t < s) red[t] = fmaxf(red[t], red[t+s]); __syncthreads(); }
    m = red[0]; __syncthreads();
    float sum = 0.0f;
    for (int k = t; k < QW; k += 256) sum += expf(q[b*QW + k] - m);
    red[t] = sum; __syncthreads();
    for (int s = 128; s > 0; s >>= 1) { if (t < s) red[t] += red[t+s]; __syncthreads(); }
    if (t == 0) out[b] = logf(red[0] + 100.0f * expf(-m)) + m;
}

extern "C" void kernel_launch(void* const* d_in, const int* in_sizes, int n_in,
                              void* d_out, int out_size, void* d_ws, size_t ws_size,
                              hipStream_t stream) {
    const float* obs     = (const float*)d_in[0];
    const float* actions = (const float*)d_in[1];
    const float* W1      = (const float*)d_in[2];
    const float* b1      = (const float*)d_in[3];
    const float* W2      = (const float*)d_in[4];
    const float* b2      = (const float*)d_in[5];
    const float* W3      = (const float*)d_in[6];
    const float* b3      = (const float*)d_in[7];
    const float* Wp      = (const float*)d_in[8];
    const float* bp      = (const float*)d_in[9];
    float* out = (float*)d_out;
    float* ws  = (float*)d_ws;

    // workspace layout (float offsets)
    unsigned short* obs_bf = (unsigned short*)(ws);            // 32768 f
    unsigned short* W1AT   = (unsigned short*)(ws + 32768);    // 786432 f
    unsigned short* W2T    = (unsigned short*)(ws + 819200);   // 786432 f
    unsigned short* W3T    = (unsigned short*)(ws + 1605632);  // 196608 f
    unsigned short* W1Cbf  = (unsigned short*)(ws + 1802240);  // 196608 f
    unsigned short* W2bf   = (unsigned short*)(ws + 1998848);  // 786432 f
    unsigned short* W3bf   = (unsigned short*)(ws + 2785280);  // 196608 f
    float* Yobs  = ws + 2981888;                               // 393216 f
    float* Y0all = ws + 3375104;                               // 393216 f
    float* CTXS  = ws + 3768320;                               // 98304 f
    float* q     = ws + 3866624;                               // 76800 f
    unsigned short* H2 = (unsigned short*)(ws + 3943424);      // 19660800 f

    cvt_kernel<<<2368, 256, 0, stream>>>(obs, W1, W2, W3, obs_bf, W1Cbf, W2bf, W3bf);
    prep_transpose<<<dim3(16,16,18), dim3(32,8), 0, stream>>>(W1, W2, W3, W1AT, W2T, W3T);
    yobs_kernel<<<dim3(2,4,6), 256, 0, stream>>>(obs_bf, W1AT, b1, Yobs);
    chain_kernel<<<BATCH, 1024, 0, stream>>>(Yobs, W1, W1Cbf, W2bf, W3bf, b2, b3, actions, Y0all, CTXS);
    h2all_kernel<<<dim3(600, 2), 256, 0, stream>>>(Y0all, W1, W2T, b2, H2);
    gemm3all_kernel<<<1200, 256, 0, stream>>>(H2, W3T, b3, CTXS, Wp, bp, q);
    lse_kernel<<<BATCH, 256, 0, stream>>>(q, out);
}

// Round 8
// 257.082 us; speedup vs baseline: 1.0480x; 1.0090x over previous
//
#include <hip/hip_runtime.h>
#include <math.h>

#define BATCH 128
#define ACT 7
#define NC 100
#define CTXD 128
#define HID 512
#define QW 600               // q width (cols 600..699 of reference are exactly 0)

typedef __attribute__((ext_vector_type(8))) __bf16 bf16x8;
typedef __attribute__((ext_vector_type(4))) float f32x4;
typedef __attribute__((ext_vector_type(8))) unsigned short u16x8;
typedef __attribute__((ext_vector_type(4))) unsigned short u16x4;

__device__ __forceinline__ unsigned short f2bf(float f) {
    union { float f; unsigned int u; } v; v.f = f;
    unsigned int u = v.u;
    return (unsigned short)((u + 0x7fffu + ((u >> 16) & 1u)) >> 16);
}

// fast round-half-up bf16: (u + 0x8000) >> 16
__device__ __forceinline__ unsigned short f2bf_fast(float f) {
    return (unsigned short)((__float_as_uint(f) + 0x8000u) >> 16);
}
// pack two floats -> two bf16 in one uint (lo = a, hi = b)
__device__ __forceinline__ unsigned int pack2bf(float a, float b) {
    unsigned int ua = __float_as_uint(a) + 0x8000u;
    unsigned int ub = __float_as_uint(b) + 0x8000u;
    return (ua >> 16) | (ub & 0xffff0000u);
}

// async global->LDS, 16B per lane. LDS dest = wave-uniform base + lane*16.
__device__ __forceinline__ void async16(const void* g, void* l) {
    __builtin_amdgcn_global_load_lds(
        (const __attribute__((address_space(1))) unsigned int*)(uintptr_t)g,
        (__attribute__((address_space(3))) unsigned int*)(unsigned int)(uintptr_t)l,
        16, 0, 0);
}

// ---------------- cvt: fp32 -> bf16 row-major copies -------------------------
__global__ void cvt_kernel(const float* __restrict__ obs, const float* __restrict__ W1,
                           const float* __restrict__ W2, const float* __restrict__ W3,
                           unsigned short* __restrict__ obs_bf, unsigned short* __restrict__ W1Cbf,
                           unsigned short* __restrict__ W2bf, unsigned short* __restrict__ W3bf) {
    const int e = (blockIdx.x * 256 + threadIdx.x) * 4;   // grid covers 2424832 elems
    const float* src; unsigned short* dst;
    if (e < 65536)        { src = obs + e; dst = obs_bf + e; }
    else if (e < 458752)  { int f = e - 65536; int i = f >> 16; int rem = f & 65535;
                            src = W1 + (size_t)(i + 1) * 328192 + 513*512 + rem; dst = W1Cbf + f; }
    else if (e < 2031616) { int f = e - 458752; src = W2 + 262144 + f; dst = W2bf + f; }
    else                  { int f = e - 2031616; src = W3 + 65536 + f; dst = W3bf + f; }
    float4 v = *(const float4*)src;
    u16x4 o; o[0] = f2bf(v.x); o[1] = f2bf(v.y); o[2] = f2bf(v.z); o[3] = f2bf(v.w);
    *(u16x4*)dst = o;
}

// ---------------- transpose+convert: W1AT / W2T / W3T ------------------------
__global__ void prep_transpose(const float* __restrict__ W1, const float* __restrict__ W2,
                               const float* __restrict__ W3,
                               unsigned short* __restrict__ W1AT, unsigned short* __restrict__ W2T,
                               unsigned short* __restrict__ W3T) {
    __shared__ float tile[32][33];
    const int z = blockIdx.z;
    const float* ip; unsigned short* op; int Cn;
    if (z < 6)       { ip = W1 + (size_t)(z + 1) * 328192; op = W1AT + (size_t)z * 262144; Cn = 512; }
    else if (z < 12) { int i = z - 6;  ip = W2 + (size_t)(i + 1) * 262144; op = W2T + (size_t)i * 262144; Cn = 512; }
    else             { int i = z - 12; ip = W3 + (size_t)(i + 1) * 65536;  op = W3T + (size_t)i * 65536;  Cn = 128;
                       if (blockIdx.y >= 4) return; }
    const int r0 = blockIdx.x * 32, c0 = blockIdx.y * 32;
    const int tx = threadIdx.x, ty = threadIdx.y;  // 32 x 8
    #pragma unroll
    for (int j = 0; j < 32; j += 8)
        tile[ty + j][tx] = ip[(size_t)(r0 + ty + j) * Cn + c0 + tx];
    __syncthreads();
    #pragma unroll
    for (int j = 0; j < 32; j += 8)
        op[(size_t)(c0 + ty + j) * 512 + r0 + tx] = f2bf(tile[tx][ty + j]);
}

// ---------------- Yobs[z][b][h] = obs@W1A[z+1] + b1[z+1] ---------------------
__launch_bounds__(256)
__global__ void yobs_kernel(const unsigned short* __restrict__ A,      // obs_bf [128][512]
                            const unsigned short* __restrict__ BtAll,  // W1AT [6][512][512]
                            const float* __restrict__ b1,
                            float* __restrict__ Yobs) {
    __shared__ unsigned short As[64*32];
    __shared__ unsigned short Bs[128*32];
    const int m0 = blockIdx.x * 64;
    const int n0 = blockIdx.y * 128;
    const int z  = blockIdx.z;
    const unsigned short* Bt = BtAll + (size_t)z * 262144;
    const int tid = threadIdx.x, lane = tid & 63, wave = tid >> 6;
    const int wm = wave >> 1, wn = wave & 1;
    const int srow = tid >> 2, skc = (tid & 3) * 8;
    const unsigned short* gA  = A  + (size_t)(m0 + srow) * HID + skc;
    const unsigned short* gB0 = Bt + (size_t)(n0 + srow) * HID + skc;
    const unsigned short* gB1 = gB0 + 64 * HID;
    f32x4 acc[2][4] = {};
    for (int k0 = 0; k0 < HID; k0 += 32) {
        async16(gA + k0, As + tid*8);
        async16(gB0 + k0, Bs + tid*8);
        async16(gB1 + k0, Bs + 2048 + tid*8);
        __syncthreads();
        const int q8 = (lane >> 4) * 8, l15 = lane & 15;
        bf16x8 af[2], bfr[4];
        #pragma unroll
        for (int mt = 0; mt < 2; ++mt)
            af[mt] = *(const bf16x8*)(As + (wm*32 + mt*16 + l15) * 32 + q8);
        #pragma unroll
        for (int nt = 0; nt < 4; ++nt)
            bfr[nt] = *(const bf16x8*)(Bs + (wn*64 + nt*16 + l15) * 32 + q8);
        #pragma unroll
        for (int mt = 0; mt < 2; ++mt)
            #pragma unroll
            for (int nt = 0; nt < 4; ++nt)
                acc[mt][nt] = __builtin_amdgcn_mfma_f32_16x16x32_bf16(af[mt], bfr[nt], acc[mt][nt], 0, 0, 0);
        __syncthreads();
    }
    const int colL = wn*64 + (lane & 15);
    #pragma unroll
    for (int nt = 0; nt < 4; ++nt) {
        const int col = n0 + colL + nt*16;
        const float bb = b1[(z + 1) * HID + col];
        #pragma unroll
        for (int mt = 0; mt < 2; ++mt)
            #pragma unroll
            for (int r = 0; r < 4; ++r) {
                const int row = m0 + wm*32 + mt*16 + (lane >> 4)*4 + r;
                Yobs[(size_t)z * 65536 + (size_t)row * HID + col] = acc[mt][nt][r] + bb;
            }
    }
}

// ---------------- chain: per-batch serial context chain, 1024 thr, split-K ---
__launch_bounds__(1024)
__global__ void chain_kernel(const float* __restrict__ Yobs, const float* __restrict__ W1,
                             const unsigned short* __restrict__ W1Cbf,
                             const unsigned short* __restrict__ W2bf,
                             const unsigned short* __restrict__ W3bf,
                             const float* __restrict__ b2, const float* __restrict__ b3,
                             const float* __restrict__ actions,
                             float* __restrict__ Y0all, float* __restrict__ CTXS) {
    const int b = blockIdx.x, t = threadIdx.x;
    __shared__ float ctx[128], h1[512], h2s[512];
    __shared__ float part[2048];      // layer1/2: [4][512]; layer3: [16][128]
    const int pair = t & 255, kq = t >> 8;      // layers 1,2
    const int pair3 = t & 63, kq3 = t >> 6;     // layer 3
    if (t < 128) ctx[t] = 0.f;
    __syncthreads();
    for (int i = 1; i <= 6; ++i) {
        if (t < 128) CTXS[(size_t)(i-1)*16384 + b*128 + t] = ctx[t];
        const float a = actions[b*ACT + i];
        float fj = floorf((a + 1.0f) * 50.0f);
        fj = fminf(fmaxf(fj, 0.0f), 99.0f);
        // ---- layer1 ctx part ----
        {
            const unsigned int* wp1 = (const unsigned int*)(W1Cbf + (size_t)(i-1)*65536) + pair;
            float acc0 = 0.f, acc1 = 0.f;
            #pragma unroll 8
            for (int k = kq*32; k < kq*32 + 32; ++k) {
                unsigned int u = wp1[k*256];
                float c = ctx[k];
                acc0 = fmaf(c, __uint_as_float(u << 16), acc0);
                acc1 = fmaf(c, __uint_as_float(u & 0xffff0000u), acc1);
            }
            *(float2*)(&part[kq*512 + 2*pair]) = make_float2(acc0, acc1);
        }
        __syncthreads();
        if (t < 256) {
            const int n2 = 2*t;
            float2 p0 = *(const float2*)(&part[n2]);
            float2 p1 = *(const float2*)(&part[512 + n2]);
            float2 p2 = *(const float2*)(&part[1024 + n2]);
            float2 p3 = *(const float2*)(&part[1536 + n2]);
            float2 yo = *(const float2*)(Yobs + (size_t)(i-1)*65536 + b*512 + n2);
            float y0a = yo.x + p0.x + p1.x + p2.x + p3.x;
            float y0b = yo.y + p0.y + p1.y + p2.y + p3.y;
            *(float2*)(Y0all + (size_t)(i-1)*65536 + b*512 + n2) = make_float2(y0a, y0b);
            const float* w1a = W1 + (size_t)i*328192 + 262144;   // row 512 of W1[i]
            float2 wv = *(const float2*)(w1a + n2);
            h1[n2]   = fmaxf(fmaf(fj, wv.x, y0a), 0.f);
            h1[n2+1] = fmaxf(fmaf(fj, wv.y, y0b), 0.f);
        }
        __syncthreads();
        // ---- layer2 ----
        {
            const unsigned int* wp2 = (const unsigned int*)(W2bf + (size_t)(i-1)*262144) + pair;
            float acc0 = 0.f, acc1 = 0.f;
            #pragma unroll 16
            for (int k = kq*128; k < kq*128 + 128; ++k) {
                unsigned int u = wp2[k*256];
                float hv = h1[k];
                acc0 = fmaf(hv, __uint_as_float(u << 16), acc0);
                acc1 = fmaf(hv, __uint_as_float(u & 0xffff0000u), acc1);
            }
            *(float2*)(&part[kq*512 + 2*pair]) = make_float2(acc0, acc1);
        }
        __syncthreads();
        if (t < 256) {
            const int n2 = 2*t;
            float2 p0 = *(const float2*)(&part[n2]);
            float2 p1 = *(const float2*)(&part[512 + n2]);
            float2 p2 = *(const float2*)(&part[1024 + n2]);
            float2 p3 = *(const float2*)(&part[1536 + n2]);
            float2 bb = *(const float2*)(b2 + i*512 + n2);
            h2s[n2]   = fmaxf(p0.x + p1.x + p2.x + p3.x + bb.x, 0.f);
            h2s[n2+1] = fmaxf(p0.y + p1.y + p2.y + p3.y + bb.y, 0.f);
        }
        __syncthreads();
        // ---- layer3 ----
        {
            const unsigned int* wp3 = (const unsigned int*)(W3bf + (size_t)(i-1)*65536) + pair3;
            float acc0 = 0.f, acc1 = 0.f;
            #pragma unroll 8
            for (int k = kq3*32; k < kq3*32 + 32; ++k) {
                unsigned int u = wp3[k*64];
                float hv = h2s[k];
                acc0 = fmaf(hv, __uint_as_float(u << 16), acc0);
                acc1 = fmaf(hv, __uint_as_float(u & 0xffff0000u), acc1);
            }
            *(float2*)(&part[kq3*128 + 2*pair3]) = make_float2(acc0, acc1);
        }
        __syncthreads();
        if (t < 128) {
            float s = 0.f;
            #pragma unroll
            for (int qg = 0; qg < 16; ++qg) s += part[qg*128 + t];
            ctx[t] = s + b3[i*128 + t] + ctx[t];
        }
        __syncthreads();
    }
}

// ---------------- h2all v5: M=128 x N=256, BK=32, SW-pipelined dbuf ----------
// One barrier per k-step: prefetch B (async16) + A (global->VGPR) for step s+1
// before the MFMAs of step s; pack A after MFMA. Drain overlaps MFMA window.
__launch_bounds__(256, 2)
__global__ void h2all_kernel(const float* __restrict__ Y0all, const float* __restrict__ W1,
                             const unsigned short* __restrict__ W2T, const float* __restrict__ b2,
                             unsigned short* __restrict__ H2) {
    __shared__ unsigned short ASl[2][128*32];   // 2 x 8 KB
    __shared__ unsigned short BSl[2][256*32];   // 2 x 16 KB
    const int bx = blockIdx.x;               // 0..599
    const int z  = bx / 100;
    const int r2 = (bx % 100) * 128;         // row within iteration z
    const int r0 = z * 12800 + r2;           // global row
    const int n0 = blockIdx.y * 256;
    const int tid = threadIdx.x, lane = tid & 63, wave = tid >> 6;
    const int wm = wave >> 1, wn = wave & 1;
    const int l15 = lane & 15, q8 = (lane >> 4) * 8;
    // A-fill: 2 chunks/thread: rows rA, rA+64, k-chunk kc8
    const int rA = tid >> 2, kc8 = (tid & 3) * 8;
    const int g1 = r2 + rA, g2 = r2 + rA + 64;
    const float c1 = (float)(g1 % 100), c2 = (float)(g2 % 100);
    const float* y1p = Y0all + (size_t)z*65536 + (size_t)(g1/100)*512 + kc8;
    const float* y2p = Y0all + (size_t)z*65536 + (size_t)(g2/100)*512 + kc8;
    const float* w1a = W1 + (size_t)(z+1)*328192 + 262144 + kc8;
    const unsigned short* Bbase = W2T + (size_t)z*262144 + (size_t)n0*512;

    float4 wa, wb, ya, yb, yc, yd;
    auto loadA = [&](int k0) {
        wa = *(const float4*)(w1a + k0); wb = *(const float4*)(w1a + k0 + 4);
        ya = *(const float4*)(y1p + k0); yb = *(const float4*)(y1p + k0 + 4);
        yc = *(const float4*)(y2p + k0); yd = *(const float4*)(y2p + k0 + 4);
    };
    auto packA = [&](int buf) {
        uint4 o;
        o.x = pack2bf(fmaxf(fmaf(c1, wa.x, ya.x), 0.f), fmaxf(fmaf(c1, wa.y, ya.y), 0.f));
        o.y = pack2bf(fmaxf(fmaf(c1, wa.z, ya.z), 0.f), fmaxf(fmaf(c1, wa.w, ya.w), 0.f));
        o.z = pack2bf(fmaxf(fmaf(c1, wb.x, yb.x), 0.f), fmaxf(fmaf(c1, wb.y, yb.y), 0.f));
        o.w = pack2bf(fmaxf(fmaf(c1, wb.z, yb.z), 0.f), fmaxf(fmaf(c1, wb.w, yb.w), 0.f));
        *(uint4*)(&ASl[buf][rA*32 + kc8]) = o;
        o.x = pack2bf(fmaxf(fmaf(c2, wa.x, yc.x), 0.f), fmaxf(fmaf(c2, wa.y, yc.y), 0.f));
        o.y = pack2bf(fmaxf(fmaf(c2, wa.z, yc.z), 0.f), fmaxf(fmaf(c2, wa.w, yc.w), 0.f));
        o.z = pack2bf(fmaxf(fmaf(c2, wb.x, yd.x), 0.f), fmaxf(fmaf(c2, wb.y, yd.y), 0.f));
        o.w = pack2bf(fmaxf(fmaf(c2, wb.z, yd.z), 0.f), fmaxf(fmaf(c2, wb.w, yd.w), 0.f));
        *(uint4*)(&ASl[buf][(rA + 64)*32 + kc8]) = o;
    };
    auto stageB = [&](int buf, int k0) {
        #pragma unroll
        for (int c = 0; c < 4; ++c) {
            const int s = c*256 + tid;
            const int col = s >> 2, sub = s & 3;
            async16(Bbase + (size_t)col*512 + k0 + sub*8, &BSl[buf][s*8]);
        }
    };

    f32x4 acc[4][8] = {};
    // prologue: stage step 0
    stageB(0, 0);
    loadA(0);
    packA(0);
    __syncthreads();
    #pragma unroll 2
    for (int s = 0; s < 16; ++s) {
        const int cur = s & 1, nxt = cur ^ 1;
        if (s < 15) { stageB(nxt, (s+1)*32); loadA((s+1)*32); }
        bf16x8 af[4], bfr[8];
        #pragma unroll
        for (int mt = 0; mt < 4; ++mt)
            af[mt] = *(const bf16x8*)(&ASl[cur][(wm*64 + mt*16 + l15)*32 + q8]);
        #pragma unroll
        for (int nt = 0; nt < 8; ++nt)
            bfr[nt] = *(const bf16x8*)(&BSl[cur][(wn*128 + nt*16 + l15)*32 + q8]);
        #pragma unroll
        for (int mt = 0; mt < 4; ++mt)
            #pragma unroll
            for (int nt = 0; nt < 8; ++nt)
                acc[mt][nt] = __builtin_amdgcn_mfma_f32_16x16x32_bf16(af[mt], bfr[nt], acc[mt][nt], 0, 0, 0);
        if (s < 15) packA(nxt);
        __syncthreads();
    }
    #pragma unroll
    for (int nt = 0; nt < 8; ++nt) {
        const int col = n0 + wn*128 + nt*16 + l15;
        const float bb = b2[(z+1)*512 + col];
        #pragma unroll
        for (int mt = 0; mt < 4; ++mt)
            #pragma unroll
            for (int r = 0; r < 4; ++r) {
                const int row = r0 + wm*64 + mt*16 + (lane >> 4)*4 + r;
                H2[(size_t)row * 512 + col] = f2bf_fast(fmaxf(acc[mt][nt][r] + bb, 0.f));
            }
    }
}

// ---------------- gemm3all v3: M=64 tiles, dbuf pipelined, fused q -----------
__launch_bounds__(256)
__global__ void gemm3all_kernel(const unsigned short* __restrict__ H2,
                                const unsigned short* __restrict__ W3T,
                                const float* __restrict__ b3, const float* __restrict__ CTXS,
                                const float* __restrict__ Wp, const float* __restrict__ bp,
                                float* __restrict__ q) {
    __shared__ unsigned short ASl[2][64*32];    // 2 x 4 KB
    __shared__ unsigned short BSl[2][128*32];   // 2 x 8 KB
    __shared__ float CCs[64][132];
    __shared__ float qp[64][4];
    const int bx = blockIdx.x;               // 0..1199
    const int z  = bx / 200;
    const int r0 = bx * 64;                  // global H2 row
    const int r2 = (bx % 200) * 64;          // row within iteration z
    const int tid = threadIdx.x, lane = tid & 63, wave = tid >> 6;
    const int wm = wave >> 1, wn = wave & 1;
    const int l15 = lane & 15, q8 = (lane >> 4) * 8;
    const unsigned short* W3Tz = W3T + (size_t)z*65536;

    auto stage = [&](int buf, int k0) {
        {
            const int s = wave*64 + lane, row = s >> 2, sub = s & 3;
            async16(H2 + (size_t)(r0 + row)*512 + k0 + sub*8, &ASl[buf][s*8]);
        }
        #pragma unroll
        for (int c = 0; c < 2; ++c) {
            const int s = c*256 + wave*64 + lane, col = s >> 2, sub = s & 3;
            async16(W3Tz + (size_t)col*512 + k0 + sub*8, &BSl[buf][s*8]);
        }
    };

    f32x4 acc[2][4] = {};
    stage(0, 0);
    __syncthreads();
    #pragma unroll 2
    for (int s = 0; s < 16; ++s) {
        const int cur = s & 1, nxt = cur ^ 1;
        if (s < 15) stage(nxt, (s+1)*32);
        bf16x8 af[2], bfr[4];
        #pragma unroll
        for (int mt = 0; mt < 2; ++mt)
            af[mt] = *(const bf16x8*)(&ASl[cur][(wm*32 + mt*16 + l15)*32 + q8]);
        #pragma unroll
        for (int nt = 0; nt < 4; ++nt)
            bfr[nt] = *(const bf16x8*)(&BSl[cur][(wn*64 + nt*16 + l15)*32 + q8]);
        #pragma unroll
        for (int mt = 0; mt < 2; ++mt)
            #pragma unroll
            for (int nt = 0; nt < 4; ++nt)
                acc[mt][nt] = __builtin_amdgcn_mfma_f32_16x16x32_bf16(af[mt], bfr[nt], acc[mt][nt], 0, 0, 0);
        __syncthreads();
    }
    #pragma unroll
    for (int nt = 0; nt < 4; ++nt) {
        const int col = wn*64 + nt*16 + l15;
        const float bb = b3[(z+1)*128 + col];
        #pragma unroll
        for (int mt = 0; mt < 2; ++mt)
            #pragma unroll
            for (int r = 0; r < 4; ++r) {
                const int rowL = wm*32 + mt*16 + (lane >> 4)*4 + r;
                const int gb = (r2 + rowL) / 100;
                CCs[rowL][col] = acc[mt][nt][r] + bb + CTXS[(size_t)z*16384 + gb*128 + col];
            }
    }
    __syncthreads();
    {
        const int rowL = tid >> 2, seg = tid & 3;
        float s = 0.f;
        #pragma unroll
        for (int j = 0; j < 32; ++j) s += CCs[rowL][seg*32 + j] * Wp[seg*32 + j];
        qp[rowL][seg] = s;
    }
    __syncthreads();
    if (tid < 64) {
        const int gr2 = r2 + tid;
        const int gb = gr2 / 100, gc = gr2 - gb * 100;
        float s = qp[tid][0] + qp[tid][1] + qp[tid][2] + qp[tid][3];
        q[gb * QW + z * 100 + gc] = s + bp[0];
    }
}

// ---------------- out[b] = logsumexp([q[b,0:600], zeros(100)]) ---------------
__global__ void lse_kernel(const float* __restrict__ q, float* __restrict__ out) {
    __shared__ float red[256];
    int b = blockIdx.x, t = threadIdx.x;
    float m = 0.0f;   // zero tail participates in the max
    for (int k = t; k < QW; k += 256) m = fmaxf(m, q[b*QW + k]);
    red[t] = m; __syncthreads();
    for (int s = 128; s > 0; s >>= 1) { if (t < s) red[t] = fmaxf(red[t], red[t+s]); __syncthreads(); }
    m = red[0]; __syncthreads();
    float sum = 0.0f;
    for (int k = t; k < QW; k += 256) sum += expf(q[b*QW + k] - m);
    red[t] = sum; __syncthreads();
    for (int s = 128; s > 0; s >>= 1) { if (t < s) red[t] += red[t+s]; __syncthreads(); }
    if (t == 0) out[b] = logf(red[0] + 100.0f * expf(-m)) + m;
}

extern "C" void kernel_launch(void* const* d_in, const int* in_sizes, int n_in,
                              void* d_out, int out_size, void* d_ws, size_t ws_size,
                              hipStream_t stream) {
    const float* obs     = (const float*)d_in[0];
    const float* actions = (const float*)d_in[1];
    const float* W1      = (const float*)d_in[2];
    const float* b1      = (const float*)d_in[3];
    const float* W2      = (const float*)d_in[4];
    const float* b2      = (const float*)d_in[5];
    const float* W3      = (const float*)d_in[6];
    const float* b3      = (const float*)d_in[7];
    const float* Wp      = (const float*)d_in[8];
    const float* bp      = (const float*)d_in[9];
    float* out = (float*)d_out;
    float* ws  = (float*)d_ws;

    // workspace layout (float offsets)
    unsigned short* obs_bf = (unsigned short*)(ws);            // 32768 f
    unsigned short* W1AT   = (unsigned short*)(ws + 32768);    // 786432 f
    unsigned short* W2T    = (unsigned short*)(ws + 819200);   // 786432 f
    unsigned short* W3T    = (unsigned short*)(ws + 1605632);  // 196608 f
    unsigned short* W1Cbf  = (unsigned short*)(ws + 1802240);  // 196608 f
    unsigned short* W2bf   = (unsigned short*)(ws + 1998848);  // 786432 f
    unsigned short* W3bf   = (unsigned short*)(ws + 2785280);  // 196608 f
    float* Yobs  = ws + 2981888;                               // 393216 f
    float* Y0all = ws + 3375104;                               // 393216 f
    float* CTXS  = ws + 3768320;                               // 98304 f
    float* q     = ws + 3866624;                               // 76800 f
    unsigned short* H2 = (unsigned short*)(ws + 3943424);      // 19660800 f

    cvt_kernel<<<2368, 256, 0, stream>>>(obs, W1, W2, W3, obs_bf, W1Cbf, W2bf, W3bf);
    prep_transpose<<<dim3(16,16,18), dim3(32,8), 0, stream>>>(W1, W2, W3, W1AT, W2T, W3T);
    yobs_kernel<<<dim3(2,4,6), 256, 0, stream>>>(obs_bf, W1AT, b1, Yobs);
    chain_kernel<<<BATCH, 1024, 0, stream>>>(Yobs, W1, W1Cbf, W2bf, W3bf, b2, b3, actions, Y0all, CTXS);
    h2all_kernel<<<dim3(600, 2), 256, 0, stream>>>(Y0all, W1, W2T, b2, H2);
    gemm3all_kernel<<<1200, 256, 0, stream>>>(H2, W3T, b3, CTXS, Wp, bp, q);
    lse_kernel<<<BATCH, 256, 0, stream>>>(q, out);
}